// Round 6
// baseline (251.566 us; speedup 1.0000x reference)
//
#include <hip/hip_runtime.h>

// Problem constants
#define B_DIM 32
#define V_DIM 21
#define D_DIM 512
#define P_DIM 64
#define M_TOTAL 672          // B*V
#define K_TOTAL 32768        // D*P
#define OUT_DIM 96
#define E_DIM 8
#define R_DIM 8
#define H_DIM 256
#define N_TOTAL 160          // OUT_DIM + E*R
#define SCALING 2.0f
#define POOL_SCALE (1.0f / (V_DIM * (float)P_DIM))

// GEMM split-K config (barrier-free, LDS-free, wave-per-16-rows)
#define KSPLIT 64
#define K_PER_SPLIT (K_TOTAL / KSPLIT)   // 512
#define KSTEPS (K_PER_SPLIT / 32)        // 16 steps of K=32
#define SMN (M_TOTAL * N_TOTAL)          // 107520 (one partial plane)
#define RC_ROWS 2                        // rows per reduce_combine block

typedef __attribute__((ext_vector_type(4))) float floatx4;
typedef __attribute__((ext_vector_type(8))) short short8;

__device__ __forceinline__ unsigned short f2bf(float f) {
  union { float f; unsigned int u; } v; v.f = f;
  unsigned int u = v.u + (0x7FFFu + ((v.u >> 16) & 1u));  // RNE
  return (unsigned short)(u >> 16);
}

// ------- convW: [W_base|lora_A] fp32 -> bf16 Wb[160][32768]; also zero pooled
__global__ __launch_bounds__(256)
void convW_kernel(const float* __restrict__ W_base, const float* __restrict__ lora_A,
                  short* __restrict__ Wb, float* __restrict__ pooled) {
  int gid = blockIdx.x * 256 + threadIdx.x;
  if (blockIdx.x < 64) pooled[gid] = 0.0f;   // 16384 floats zeroed (grid is 2560 blocks)
  size_t base = (size_t)gid * 8;             // 5.24M shorts total
  int row = (int)(base >> 15);
  int k = (int)(base & 32767);
  const float* src = (row < OUT_DIM) ? (W_base + ((size_t)row << 15) + k)
                                     : (lora_A + ((size_t)(row - OUT_DIM) << 15) + k);
  floatx4 v0 = ((const floatx4*)src)[0];
  floatx4 v1 = ((const floatx4*)src)[1];
  short8 sv;
  sv[0] = (short)f2bf(v0[0]); sv[1] = (short)f2bf(v0[1]);
  sv[2] = (short)f2bf(v0[2]); sv[3] = (short)f2bf(v0[3]);
  sv[4] = (short)f2bf(v1[0]); sv[5] = (short)f2bf(v1[1]);
  sv[6] = (short)f2bf(v1[2]); sv[7] = (short)f2bf(v1[3]);
  *(short8*)(Wb + base) = sv;
}

// ------- gemm: P[ky][m][n] = x-chunk @ Wb^T (no LDS, no barriers, no S-atomics)
// wave handles 16 m-rows x all 160 n over K range [ky*512, +512).
// Lane's loaded x values ARE its A-fragment: A[m=lane&15][k=(lane>>4)*8+j].
__global__ __launch_bounds__(256, 3)
void gemm_kernel(const float* __restrict__ x, const short* __restrict__ Wb,
                 float* __restrict__ P, float* __restrict__ pooled) {
  const int tid = threadIdx.x;
  const int wave = tid >> 6;
  const int lane = tid & 63;
  const int quad = lane >> 4;
  const int l16 = lane & 15;
  const int m0w = blockIdx.x * 64 + wave * 16;
  if (m0w >= M_TOTAL) return;               // 2 dead wave-slots in last block
  const int ky = blockIdx.y;
  const int kbase = ky * K_PER_SPLIT;
  const int m = m0w + l16;                  // this lane's A row
  const int bb = m / V_DIM;
  const float* xp = x + (size_t)m * K_TOTAL + kbase + quad * 8;
  const short* wp = Wb + (size_t)l16 * K_TOTAL + kbase + quad * 8;

  floatx4 acc[10];
  #pragma unroll
  for (int nt = 0; nt < 10; ++nt) acc[nt] = (floatx4)(0.0f);

  floatx4 a0 = ((const floatx4*)xp)[0];     // k+0..3
  floatx4 a1 = *(const floatx4*)(xp + 4);   // k+4..7
  float dsum = 0.0f;

  #pragma unroll
  for (int c = 0; c < KSTEPS; ++c) {
    // prefetch next step's A (HBM) so its latency hides under this step
    floatx4 n0 = (floatx4)(0.0f), n1 = (floatx4)(0.0f);
    if (c + 1 < KSTEPS) {
      n0 = *(const floatx4*)(xp + (c + 1) * 32);
      n1 = *(const floatx4*)(xp + (c + 1) * 32 + 4);
    }
    // B fragments straight from global (IF$-resident; L1-shared across waves)
    short8 pb[10];
    #pragma unroll
    for (int nt = 0; nt < 10; ++nt)
      pb[nt] = *(const short8*)(wp + (size_t)nt * 16 * K_TOTAL + c * 32);
    // convert A in-register -> fragment
    short8 af;
    af[0] = (short)f2bf(a0[0]); af[1] = (short)f2bf(a0[1]);
    af[2] = (short)f2bf(a0[2]); af[3] = (short)f2bf(a0[3]);
    af[4] = (short)f2bf(a1[0]); af[5] = (short)f2bf(a1[1]);
    af[6] = (short)f2bf(a1[2]); af[7] = (short)f2bf(a1[3]);
    #pragma unroll
    for (int nt = 0; nt < 10; ++nt)
      acc[nt] = __builtin_amdgcn_mfma_f32_16x16x32_bf16(af, pb[nt], acc[nt], 0, 0, 0);
    // pooling: one 32-k step = half of one d-run; reduce across quads
    float s8 = ((a0[0] + a0[1]) + (a0[2] + a0[3])) +
               ((a1[0] + a1[1]) + (a1[2] + a1[3]));
    s8 += __shfl_xor(s8, 16, 64);
    s8 += __shfl_xor(s8, 32, 64);
    if ((c & 1) == 0) {
      dsum = s8;
    } else if (quad == 0) {
      int d = (kbase >> 6) + (c >> 1);
      atomicAdd(&pooled[bb * D_DIM + d], (dsum + s8) * POOL_SCALE);
    }
    a0 = n0; a1 = n1;
  }

  // store partial tile (D layout: col=lane&15, row=quad*4+reg) — plain stores
  float* Pp = P + (size_t)ky * SMN + (size_t)(m0w + quad * 4) * N_TOTAL + l16;
  #pragma unroll
  for (int r = 0; r < 4; ++r)
    #pragma unroll
    for (int nt = 0; nt < 10; ++nt)
      Pp[(size_t)r * N_TOTAL + nt * 16] = acc[nt][r];
}

// ---------------- router: MLP + softmax + top-2 ------------------------------
__global__ __launch_bounds__(256)
void router_kernel(const float* __restrict__ pooled, const float* __restrict__ W1,
                   const float* __restrict__ b1, const float* __restrict__ W2,
                   const float* __restrict__ b2, float* __restrict__ wfull,
                   float* __restrict__ probs_out) {
  __shared__ float sp[D_DIM];
  __shared__ float sh[H_DIM];
  __shared__ float slog[E_DIM];
  const int b = blockIdx.x;
  const int t = threadIdx.x;
  sp[t] = pooled[b * D_DIM + t];
  sp[t + 256] = pooled[b * D_DIM + t + 256];
  __syncthreads();
  float acc = b1[t];
  const float* w1r = W1 + (size_t)t * D_DIM;
  for (int d = 0; d < D_DIM; ++d) acc += sp[d] * w1r[d];
  sh[t] = fmaxf(acc, 0.0f);
  __syncthreads();
  if (t < E_DIM) {
    float a = b2[t];
    const float* w2r = W2 + t * H_DIM;
    for (int j = 0; j < H_DIM; ++j) a += sh[j] * w2r[j];
    slog[t] = a;
  }
  __syncthreads();
  if (t == 0) {
    float p[E_DIM];
    float mx = slog[0];
    for (int e = 1; e < E_DIM; ++e) mx = fmaxf(mx, slog[e]);
    float se = 0.0f;
    for (int e = 0; e < E_DIM; ++e) { p[e] = __expf(slog[e] - mx); se += p[e]; }
    float inv = 1.0f / se;
    for (int e = 0; e < E_DIM; ++e) { p[e] *= inv; probs_out[b * E_DIM + e] = p[e]; }
    // top-2, lowest index wins ties (strict > keeps earlier index)
    int i0 = 0;
    for (int e = 1; e < E_DIM; ++e) if (p[e] > p[i0]) i0 = e;
    int i1 = (i0 == 0) ? 1 : 0;
    for (int e = 0; e < E_DIM; ++e) if (e != i0 && p[e] > p[i1]) i1 = e;
    float s2 = p[i0] + p[i1];
    float invs = 1.0f / fmaxf(s2, 1e-6f);
    for (int e = 0; e < E_DIM; ++e) {
      float w = 0.0f;
      if (e == i0) w += p[i0] * invs;
      if (e == i1) w += p[i1] * invs;
      wfull[b * E_DIM + e] = w;
    }
  }
}

// ------- reduce partials over KSPLIT + combine: out = S_b + b_base + 2*Σ w·(S_l·B)
__global__ __launch_bounds__(256)
void reduce_combine_kernel(const float* __restrict__ P, const float* __restrict__ b_base,
                           const float* __restrict__ lora_B, const float* __restrict__ wfull,
                           float* __restrict__ out) {
  __shared__ float sS[RC_ROWS * N_TOTAL];   // 320 floats
  const int t = threadIdx.x;
  const size_t base = (size_t)blockIdx.x * (RC_ROWS * N_TOTAL);
  for (int s = t; s < RC_ROWS * N_TOTAL; s += 256) {
    const float* Pp = P + base + s;
    float a = 0.0f;
    #pragma unroll 8
    for (int k = 0; k < KSPLIT; ++k) a += Pp[(size_t)k * SMN];
    sS[s] = a;
  }
  __syncthreads();
  if (t < RC_ROWS * OUT_DIM) {
    int mr = t / OUT_DIM;
    int o = t - mr * OUT_DIM;
    int mm = blockIdx.x * RC_ROWS + mr;
    int b = mm / V_DIM;
    const float* srow = sS + mr * N_TOTAL;
    float res = srow[o] + b_base[o];
    float moe = 0.0f;
    #pragma unroll
    for (int e = 0; e < E_DIM; ++e) {
      float we = wfull[b * E_DIM + e];
      if (we != 0.0f) {
        const float* lb = lora_B + ((size_t)e * OUT_DIM + o) * R_DIM;
        float dd = 0.0f;
        #pragma unroll
        for (int r = 0; r < R_DIM; ++r) dd += srow[OUT_DIM + e * R_DIM + r] * lb[r];
        moe += we * dd;
      }
    }
    out[(size_t)mm * OUT_DIM + o] = res + SCALING * moe;
  }
}

extern "C" void kernel_launch(void* const* d_in, const int* in_sizes, int n_in,
                              void* d_out, int out_size, void* d_ws, size_t ws_size,
                              hipStream_t stream) {
  const float* x      = (const float*)d_in[0];
  const float* W_base = (const float*)d_in[1];
  const float* b_base = (const float*)d_in[2];
  const float* W1     = (const float*)d_in[3];
  const float* b1     = (const float*)d_in[4];
  const float* W2     = (const float*)d_in[5];
  const float* b2     = (const float*)d_in[6];
  const float* lora_A = (const float*)d_in[7];
  const float* lora_B = (const float*)d_in[8];
  float* out = (float*)d_out;

  // ws layout: pooled[16384 f] | wfull[256 f] | Wb[160*32768 bf16] | P[64*107520 f]
  float* ws     = (float*)d_ws;
  float* pooled = ws;
  float* wfull  = ws + 16384;
  short* Wb     = (short*)(wfull + 256);
  float* P      = (float*)(Wb + (size_t)N_TOTAL * K_TOTAL);

  convW_kernel<<<(N_TOTAL * K_TOTAL / 8 + 255) / 256, 256, 0, stream>>>(
      W_base, lora_A, Wb, pooled);
  gemm_kernel<<<dim3(11, KSPLIT), 256, 0, stream>>>(x, Wb, P, pooled);
  router_kernel<<<B_DIM, 256, 0, stream>>>(pooled, W1, b1, W2, b2, wfull,
                                           out + (size_t)M_TOTAL * OUT_DIM);
  reduce_combine_kernel<<<M_TOTAL / RC_ROWS, 256, 0, stream>>>(
      P, b_base, lora_B, wfull, out);
}

// Round 7
// 207.001 us; speedup vs baseline: 1.2153x; 1.2153x over previous
//
#include <hip/hip_runtime.h>

// Problem constants
#define B_DIM 32
#define V_DIM 21
#define D_DIM 512
#define P_DIM 64
#define M_TOTAL 672          // B*V
#define K_TOTAL 32768        // D*P
#define OUT_DIM 96
#define E_DIM 8
#define R_DIM 8
#define H_DIM 256
#define N_TOTAL 160          // OUT_DIM + E*R
#define SCALING 2.0f
#define POOL_SCALE (1.0f / (V_DIM * (float)P_DIM))

// GEMM tiling: everything staged through LDS, fully coalesced global access.
#define BM 64
#define BK 128
#define KSPLIT 32
#define K_PER_SPLIT (K_TOTAL / KSPLIT)   // 1024
#define CHUNKS (K_PER_SPLIT / BK)        // 8
#define LDS_K (BK + 8)                   // 136 shorts/row: 2-way bank alias only (free)
#define SMN (M_TOTAL * N_TOTAL)          // 107520 per partial plane
#define RC_ROWS 2                        // rows per reduce_combine block

typedef __attribute__((ext_vector_type(4))) float floatx4;
typedef __attribute__((ext_vector_type(8))) short short8;
typedef __attribute__((ext_vector_type(4))) short shortx4;  // 'short4' is a HIP builtin

__device__ __forceinline__ unsigned short f2bf(float f) {
  union { float f; unsigned int u; } v; v.f = f;
  unsigned int u = v.u + (0x7FFFu + ((v.u >> 16) & 1u));  // RNE
  return (unsigned short)(u >> 16);
}

// ------- convW: [W_base|lora_A] fp32 -> bf16 Wb[160][32768]; also zero pooled
__global__ __launch_bounds__(256)
void convW_kernel(const float* __restrict__ W_base, const float* __restrict__ lora_A,
                  short* __restrict__ Wb, float* __restrict__ pooled) {
  int gid = blockIdx.x * 256 + threadIdx.x;
  if (blockIdx.x < 64) pooled[gid] = 0.0f;   // 16384 floats zeroed (grid is 2560 blocks)
  size_t base = (size_t)gid * 8;
  int row = (int)(base >> 15);
  int k = (int)(base & 32767);
  const float* src = (row < OUT_DIM) ? (W_base + ((size_t)row << 15) + k)
                                     : (lora_A + ((size_t)(row - OUT_DIM) << 15) + k);
  floatx4 v0 = ((const floatx4*)src)[0];
  floatx4 v1 = ((const floatx4*)src)[1];
  short8 sv;
  sv[0] = (short)f2bf(v0[0]); sv[1] = (short)f2bf(v0[1]);
  sv[2] = (short)f2bf(v0[2]); sv[3] = (short)f2bf(v0[3]);
  sv[4] = (short)f2bf(v1[0]); sv[5] = (short)f2bf(v1[1]);
  sv[6] = (short)f2bf(v1[2]); sv[7] = (short)f2bf(v1[3]);
  *(short8*)(Wb + base) = sv;
}

// ------- gemm: P[ky][m][n] = x-chunk @ Wb^T; A,B staged via LDS (coalesced);
// plain-store partials (no S atomics); pooling fused via shuffle tree.
__global__ __launch_bounds__(256, 2)
void gemm_kernel(const float* __restrict__ x, const short* __restrict__ Wb,
                 float* __restrict__ P, float* __restrict__ pooled) {
  __shared__ short ldsA[BM * LDS_K];      // 17,408 B
  __shared__ short ldsB[N_TOTAL * LDS_K]; // 43,520 B
  __shared__ float lds_pool[5 * 16];      // [b_local][d_local]; K range spans 16 d
  const int tid = threadIdx.x;
  const int m0 = blockIdx.x * BM;
  const int ky = blockIdx.y;
  const int kbase = ky * K_PER_SPLIT;
  const int lane = tid & 63;
  const int wave = tid >> 6;
  const int quad = lane >> 4;
  const int l16 = lane & 15;
  const int b_first = m0 / V_DIM;
  const int d_first = kbase >> 6;         // k = d*64 + p

  if (tid < 80) lds_pool[tid] = 0.0f;

  floatx4 acc[10];                        // wave: rows [wave*16,+16), all 160 n
  #pragma unroll
  for (int nt = 0; nt < 10; ++nt) acc[nt] = (floatx4)(0.0f);

  // staging coords: A: idx=it*256+tid -> arow=idx>>5, u=idx&31 (float4 units;
  // 16-thread groups share (row, d-half)); B: brow=idx>>4, g=idx&15 (short8).
  floatx4 pa[8];
  short8 pb[10];

#define ISSUE(c)                                                                \
  {                                                                             \
    const int kc = kbase + (c) * BK;                                            \
    _Pragma("unroll")                                                           \
    for (int it = 0; it < 8; ++it) {                                            \
      int idx = it * 256 + tid;                                                 \
      int arow = idx >> 5;                                                      \
      int u = idx & 31;                                                         \
      int m = m0 + arow;                                                        \
      pa[it] = (m < M_TOTAL)                                                    \
          ? *(const floatx4*)(x + (size_t)m * K_TOTAL + kc + u * 4)             \
          : (floatx4)(0.0f);                                                    \
    }                                                                           \
    _Pragma("unroll")                                                           \
    for (int it = 0; it < 10; ++it) {                                           \
      int idx = it * 256 + tid;                                                 \
      int brow = idx >> 4;                                                      \
      int g = idx & 15;                                                         \
      pb[it] = *(const short8*)(Wb + (size_t)brow * K_TOTAL + kc + g * 8);      \
    }                                                                           \
  }

#define CONVERT_WRITE(c)                                                        \
  {                                                                             \
    _Pragma("unroll")                                                           \
    for (int it = 0; it < 8; ++it) {                                            \
      int idx = it * 256 + tid;                                                 \
      int arow = idx >> 5;                                                      \
      int u = idx & 31;                                                         \
      int m = m0 + arow;                                                        \
      floatx4 v = pa[it];                                                       \
      /* pooling: 16-thread group = one (row, d-half); one LDS atomic/group */  \
      float s = (v[0] + v[1]) + (v[2] + v[3]);                                  \
      s += __shfl_down(s, 8, 16);                                               \
      s += __shfl_down(s, 4, 16);                                               \
      s += __shfl_down(s, 2, 16);                                               \
      s += __shfl_down(s, 1, 16);                                               \
      if ((tid & 15) == 0 && m < M_TOTAL) {                                     \
        int b_local = (m / V_DIM) - b_first;                                    \
        int d_local = (c) * 2 + (u >> 4);                                       \
        atomicAdd(&lds_pool[b_local * 16 + d_local], s);                        \
      }                                                                         \
      shortx4 sv;                                                               \
      sv[0] = (short)f2bf(v[0]); sv[1] = (short)f2bf(v[1]);                     \
      sv[2] = (short)f2bf(v[2]); sv[3] = (short)f2bf(v[3]);                     \
      *(shortx4*)&ldsA[arow * LDS_K + u * 4] = sv;                              \
    }                                                                           \
    _Pragma("unroll")                                                           \
    for (int it = 0; it < 10; ++it) {                                           \
      int idx = it * 256 + tid;                                                 \
      int brow = idx >> 4;                                                      \
      int g = idx & 15;                                                         \
      *(short8*)&ldsB[brow * LDS_K + g * 8] = pb[it];                           \
    }                                                                           \
  }

  ISSUE(0);
  __syncthreads();          // lds_pool zeros visible before first atomicAdd
  CONVERT_WRITE(0);

  for (int c = 0; c < CHUNKS; ++c) {
    __syncthreads();        // LDS tiles for chunk c ready
    if (c + 1 < CHUNKS) ISSUE(c + 1);     // next chunk's loads fly under MFMA
    #pragma unroll
    for (int ks = 0; ks < 4; ++ks) {
      const int ko = ks * 32 + quad * 8;
      short8 a = *(const short8*)&ldsA[(wave * 16 + l16) * LDS_K + ko];
      #pragma unroll
      for (int nt = 0; nt < 10; ++nt) {
        short8 b = *(const short8*)&ldsB[(nt * 16 + l16) * LDS_K + ko];
        acc[nt] = __builtin_amdgcn_mfma_f32_16x16x32_bf16(a, b, acc[nt], 0, 0, 0);
      }
    }
    __syncthreads();        // all LDS reads of chunk c done
    if (c + 1 < CHUNKS) CONVERT_WRITE(c + 1);
  }

  // partial-plane store (D layout: col=lane&15, row=quad*4+reg) — plain stores
  {
    const int mrow = m0 + wave * 16 + quad * 4;
    float* Pp = P + (size_t)ky * SMN + (size_t)mrow * N_TOTAL + l16;
    #pragma unroll
    for (int r = 0; r < 4; ++r)
      if (mrow + r < M_TOTAL)
        #pragma unroll
        for (int nt = 0; nt < 10; ++nt)
          Pp[(size_t)r * N_TOTAL + nt * 16] = acc[nt][r];
  }

  // pooled partials -> global (80 atomics/block)
  if (tid < 80) {
    int b = b_first + (tid >> 4);
    int d = d_first + (tid & 15);
    if (b < B_DIM)
      atomicAdd(&pooled[b * D_DIM + d], lds_pool[tid] * POOL_SCALE);
  }
}

// ---------------- router: MLP + softmax + top-2 ------------------------------
__global__ __launch_bounds__(256)
void router_kernel(const float* __restrict__ pooled, const float* __restrict__ W1,
                   const float* __restrict__ b1, const float* __restrict__ W2,
                   const float* __restrict__ b2, float* __restrict__ wfull,
                   float* __restrict__ probs_out) {
  __shared__ float sp[D_DIM];
  __shared__ float sh[H_DIM];
  __shared__ float slog[E_DIM];
  const int b = blockIdx.x;
  const int t = threadIdx.x;
  sp[t] = pooled[b * D_DIM + t];
  sp[t + 256] = pooled[b * D_DIM + t + 256];
  __syncthreads();
  float acc = b1[t];
  const float* w1r = W1 + (size_t)t * D_DIM;
  for (int d = 0; d < D_DIM; ++d) acc += sp[d] * w1r[d];
  sh[t] = fmaxf(acc, 0.0f);
  __syncthreads();
  if (t < E_DIM) {
    float a = b2[t];
    const float* w2r = W2 + t * H_DIM;
    for (int j = 0; j < H_DIM; ++j) a += sh[j] * w2r[j];
    slog[t] = a;
  }
  __syncthreads();
  if (t == 0) {
    float p[E_DIM];
    float mx = slog[0];
    for (int e = 1; e < E_DIM; ++e) mx = fmaxf(mx, slog[e]);
    float se = 0.0f;
    for (int e = 0; e < E_DIM; ++e) { p[e] = __expf(slog[e] - mx); se += p[e]; }
    float inv = 1.0f / se;
    for (int e = 0; e < E_DIM; ++e) { p[e] *= inv; probs_out[b * E_DIM + e] = p[e]; }
    // top-2, lowest index wins ties (strict > keeps earlier index)
    int i0 = 0;
    for (int e = 1; e < E_DIM; ++e) if (p[e] > p[i0]) i0 = e;
    int i1 = (i0 == 0) ? 1 : 0;
    for (int e = 0; e < E_DIM; ++e) if (e != i0 && p[e] > p[i1]) i1 = e;
    float s2 = p[i0] + p[i1];
    float invs = 1.0f / fmaxf(s2, 1e-6f);
    for (int e = 0; e < E_DIM; ++e) {
      float w = 0.0f;
      if (e == i0) w += p[i0] * invs;
      if (e == i1) w += p[i1] * invs;
      wfull[b * E_DIM + e] = w;
    }
  }
}

// ------- reduce partials over KSPLIT + combine: out = S_b + b_base + 2*Σ w·(S_l·B)
__global__ __launch_bounds__(256)
void reduce_combine_kernel(const float* __restrict__ P, const float* __restrict__ b_base,
                           const float* __restrict__ lora_B, const float* __restrict__ wfull,
                           float* __restrict__ out) {
  __shared__ float sS[RC_ROWS * N_TOTAL];   // 320 floats
  const int t = threadIdx.x;
  const size_t base = (size_t)blockIdx.x * (RC_ROWS * N_TOTAL);
  for (int s = t; s < RC_ROWS * N_TOTAL; s += 256) {
    const float* Pp = P + base + s;
    float a = 0.0f;
    #pragma unroll 8
    for (int k = 0; k < KSPLIT; ++k) a += Pp[(size_t)k * SMN];
    sS[s] = a;
  }
  __syncthreads();
  if (t < RC_ROWS * OUT_DIM) {
    int mr = t / OUT_DIM;
    int o = t - mr * OUT_DIM;
    int mm = blockIdx.x * RC_ROWS + mr;
    int b = mm / V_DIM;
    const float* srow = sS + mr * N_TOTAL;
    float res = srow[o] + b_base[o];
    float moe = 0.0f;
    #pragma unroll
    for (int e = 0; e < E_DIM; ++e) {
      float we = wfull[b * E_DIM + e];
      if (we != 0.0f) {
        const float* lb = lora_B + ((size_t)e * OUT_DIM + o) * R_DIM;
        float dd = 0.0f;
        #pragma unroll
        for (int r = 0; r < R_DIM; ++r) dd += srow[OUT_DIM + e * R_DIM + r] * lb[r];
        moe += we * dd;
      }
    }
    out[(size_t)mm * OUT_DIM + o] = res + SCALING * moe;
  }
}

extern "C" void kernel_launch(void* const* d_in, const int* in_sizes, int n_in,
                              void* d_out, int out_size, void* d_ws, size_t ws_size,
                              hipStream_t stream) {
  const float* x      = (const float*)d_in[0];
  const float* W_base = (const float*)d_in[1];
  const float* b_base = (const float*)d_in[2];
  const float* W1     = (const float*)d_in[3];
  const float* b1     = (const float*)d_in[4];
  const float* W2     = (const float*)d_in[5];
  const float* b2     = (const float*)d_in[6];
  const float* lora_A = (const float*)d_in[7];
  const float* lora_B = (const float*)d_in[8];
  float* out = (float*)d_out;

  // ws layout: pooled[16384 f] | wfull[256 f] | Wb[160*32768 bf16] | P[32*107520 f]
  float* ws     = (float*)d_ws;
  float* pooled = ws;
  float* wfull  = ws + 16384;
  short* Wb     = (short*)(wfull + 256);
  float* P      = (float*)(Wb + (size_t)N_TOTAL * K_TOTAL);

  convW_kernel<<<(N_TOTAL * K_TOTAL / 8 + 255) / 256, 256, 0, stream>>>(
      W_base, lora_A, Wb, pooled);
  gemm_kernel<<<dim3(11, KSPLIT), 256, 0, stream>>>(x, Wb, P, pooled);
  router_kernel<<<B_DIM, 256, 0, stream>>>(pooled, W1, b1, W2, b2, wfull,
                                           out + (size_t)M_TOTAL * OUT_DIM);
  reduce_combine_kernel<<<M_TOTAL / RC_ROWS, 256, 0, stream>>>(
      P, b_base, lora_B, wfull, out);
}

// Round 8
// 205.512 us; speedup vs baseline: 1.2241x; 1.0072x over previous
//
#include <hip/hip_runtime.h>

// Problem constants
#define B_DIM 32
#define V_DIM 21
#define D_DIM 512
#define P_DIM 64
#define M_TOTAL 672          // B*V
#define K_TOTAL 32768        // D*P
#define OUT_DIM 96
#define E_DIM 8
#define R_DIM 8
#define H_DIM 256
#define N_TOTAL 160          // OUT_DIM + E*R
#define SCALING 2.0f
#define POOL_SCALE (1.0f / (V_DIM * (float)P_DIM))

// GEMM tiling: coalesced LDS staging, small tiles for residency.
#define BM 64
#define BK 64
#define KSPLIT 64
#define K_PER_SPLIT (K_TOTAL / KSPLIT)   // 512
#define CHUNKS (K_PER_SPLIT / BK)        // 8
#define LDS_K (BK + 8)                   // 72 shorts/row: row stride 144B -> 4-bank rotate
#define SMN (M_TOTAL * N_TOTAL)          // 107520 per partial plane
#define RC_ROWS 2                        // rows per reduce_combine block

typedef __attribute__((ext_vector_type(4))) float floatx4;
typedef __attribute__((ext_vector_type(8))) short short8;
typedef __attribute__((ext_vector_type(4))) short shortx4;  // 'short4' is a HIP builtin

__device__ __forceinline__ unsigned short f2bf(float f) {
  union { float f; unsigned int u; } v; v.f = f;
  unsigned int u = v.u + (0x7FFFu + ((v.u >> 16) & 1u));  // RNE
  return (unsigned short)(u >> 16);
}

// ------- convW: [W_base|lora_A] fp32 -> bf16 Wb[160][32768]; also zero pooled
__global__ __launch_bounds__(256)
void convW_kernel(const float* __restrict__ W_base, const float* __restrict__ lora_A,
                  short* __restrict__ Wb, float* __restrict__ pooled) {
  int gid = blockIdx.x * 256 + threadIdx.x;
  if (blockIdx.x < 64) pooled[gid] = 0.0f;   // 16384 floats zeroed (grid is 2560 blocks)
  size_t base = (size_t)gid * 8;
  int row = (int)(base >> 15);
  int k = (int)(base & 32767);
  const float* src = (row < OUT_DIM) ? (W_base + ((size_t)row << 15) + k)
                                     : (lora_A + ((size_t)(row - OUT_DIM) << 15) + k);
  floatx4 v0 = ((const floatx4*)src)[0];
  floatx4 v1 = ((const floatx4*)src)[1];
  short8 sv;
  sv[0] = (short)f2bf(v0[0]); sv[1] = (short)f2bf(v0[1]);
  sv[2] = (short)f2bf(v0[2]); sv[3] = (short)f2bf(v0[3]);
  sv[4] = (short)f2bf(v1[0]); sv[5] = (short)f2bf(v1[1]);
  sv[6] = (short)f2bf(v1[2]); sv[7] = (short)f2bf(v1[3]);
  *(short8*)(Wb + base) = sv;
}

// ------- gemm: P[ky][m][n] = x-chunk @ Wb^T; A,B staged via LDS (coalesced);
// plain-store partials; pooling fused via shuffle tree. 4 blocks/CU resident.
__global__ __launch_bounds__(256, 4)
void gemm_kernel(const float* __restrict__ x, const short* __restrict__ Wb,
                 float* __restrict__ P, float* __restrict__ pooled) {
  __shared__ short ldsA[BM * LDS_K];      //  9,216 B
  __shared__ short ldsB[N_TOTAL * LDS_K]; // 23,040 B
  __shared__ float lds_pool[5 * 8];       // [b_local][d_local = chunk]
  const int tid = threadIdx.x;
  const int m0 = blockIdx.x * BM;
  const int ky = blockIdx.y;
  const int kbase = ky * K_PER_SPLIT;
  const int lane = tid & 63;
  const int wave = tid >> 6;
  const int quad = lane >> 4;
  const int l16 = lane & 15;
  const int b_first = m0 / V_DIM;
  const int d_first = kbase >> 6;         // k = d*64 + p; one chunk == one d

  if (tid < 40) lds_pool[tid] = 0.0f;

  floatx4 acc[10];                        // wave: rows [wave*16,+16), all 160 n
  #pragma unroll
  for (int nt = 0; nt < 10; ++nt) acc[nt] = (floatx4)(0.0f);

  // staging coords: A: idx=it*256+tid -> arow=idx>>4, u=idx&15 (float4 units;
  // 16-thread group = one row = one d). B: brow=idx>>3, g=idx&7 (short8 units).
  floatx4 pa[4];
  short8 pb[5];

#define ISSUE(c)                                                                \
  {                                                                             \
    const int kc = kbase + (c) * BK;                                            \
    _Pragma("unroll")                                                           \
    for (int it = 0; it < 4; ++it) {                                            \
      int idx = it * 256 + tid;                                                 \
      int arow = idx >> 4;                                                      \
      int u = idx & 15;                                                         \
      int m = m0 + arow;                                                        \
      pa[it] = (m < M_TOTAL)                                                    \
          ? *(const floatx4*)(x + (size_t)m * K_TOTAL + kc + u * 4)             \
          : (floatx4)(0.0f);                                                    \
    }                                                                           \
    _Pragma("unroll")                                                           \
    for (int it = 0; it < 5; ++it) {                                            \
      int idx = it * 256 + tid;                                                 \
      int brow = idx >> 3;                                                      \
      int g = idx & 7;                                                          \
      pb[it] = *(const short8*)(Wb + (size_t)brow * K_TOTAL + kc + g * 8);      \
    }                                                                           \
  }

#define CONVERT_WRITE(c)                                                        \
  {                                                                             \
    _Pragma("unroll")                                                           \
    for (int it = 0; it < 4; ++it) {                                            \
      int idx = it * 256 + tid;                                                 \
      int arow = idx >> 4;                                                      \
      int u = idx & 15;                                                         \
      int m = m0 + arow;                                                        \
      floatx4 v = pa[it];                                                       \
      /* pooling: 16-thread group = one (row, d); one LDS atomic per group */   \
      float s = (v[0] + v[1]) + (v[2] + v[3]);                                  \
      s += __shfl_down(s, 8, 16);                                               \
      s += __shfl_down(s, 4, 16);                                               \
      s += __shfl_down(s, 2, 16);                                               \
      s += __shfl_down(s, 1, 16);                                               \
      if ((tid & 15) == 0 && m < M_TOTAL) {                                     \
        int b_local = (m / V_DIM) - b_first;                                    \
        atomicAdd(&lds_pool[b_local * 8 + (c)], s);                             \
      }                                                                         \
      shortx4 sv;                                                               \
      sv[0] = (short)f2bf(v[0]); sv[1] = (short)f2bf(v[1]);                     \
      sv[2] = (short)f2bf(v[2]); sv[3] = (short)f2bf(v[3]);                     \
      *(shortx4*)&ldsA[arow * LDS_K + u * 4] = sv;                              \
    }                                                                           \
    _Pragma("unroll")                                                           \
    for (int it = 0; it < 5; ++it) {                                            \
      int idx = it * 256 + tid;                                                 \
      int brow = idx >> 3;                                                      \
      int g = idx & 7;                                                          \
      *(short8*)&ldsB[brow * LDS_K + g * 8] = pb[it];                           \
    }                                                                           \
  }

  ISSUE(0);
  __syncthreads();          // lds_pool zeros visible before first atomicAdd
  CONVERT_WRITE(0);

  for (int c = 0; c < CHUNKS; ++c) {
    __syncthreads();        // LDS tiles for chunk c ready
    if (c + 1 < CHUNKS) ISSUE(c + 1);     // next chunk's loads fly under MFMA
    #pragma unroll
    for (int ks = 0; ks < 2; ++ks) {
      const int ko = ks * 32 + quad * 8;
      short8 a = *(const short8*)&ldsA[(wave * 16 + l16) * LDS_K + ko];
      #pragma unroll
      for (int nt = 0; nt < 10; ++nt) {
        short8 b = *(const short8*)&ldsB[(nt * 16 + l16) * LDS_K + ko];
        acc[nt] = __builtin_amdgcn_mfma_f32_16x16x32_bf16(a, b, acc[nt], 0, 0, 0);
      }
    }
    __syncthreads();        // all LDS reads of chunk c done
    if (c + 1 < CHUNKS) CONVERT_WRITE(c + 1);
  }

  // partial-plane store (D layout: col=lane&15, row=quad*4+reg) — plain stores
  {
    const int mrow = m0 + wave * 16 + quad * 4;
    float* Pp = P + (size_t)ky * SMN + (size_t)mrow * N_TOTAL + l16;
    #pragma unroll
    for (int r = 0; r < 4; ++r)
      if (mrow + r < M_TOTAL)
        #pragma unroll
        for (int nt = 0; nt < 10; ++nt)
          Pp[(size_t)r * N_TOTAL + nt * 16] = acc[nt][r];
  }

  // pooled partials -> global (40 atomics/block)
  if (tid < 40) {
    int b = b_first + (tid >> 3);
    int d = d_first + (tid & 7);
    if (b < B_DIM)
      atomicAdd(&pooled[b * D_DIM + d], lds_pool[tid] * POOL_SCALE);
  }
}

// ---------------- router: MLP + softmax + top-2 ------------------------------
__global__ __launch_bounds__(256)
void router_kernel(const float* __restrict__ pooled, const float* __restrict__ W1,
                   const float* __restrict__ b1, const float* __restrict__ W2,
                   const float* __restrict__ b2, float* __restrict__ wfull,
                   float* __restrict__ probs_out) {
  __shared__ float sp[D_DIM];
  __shared__ float sh[H_DIM];
  __shared__ float slog[E_DIM];
  const int b = blockIdx.x;
  const int t = threadIdx.x;
  sp[t] = pooled[b * D_DIM + t];
  sp[t + 256] = pooled[b * D_DIM + t + 256];
  __syncthreads();
  float acc = b1[t];
  const float* w1r = W1 + (size_t)t * D_DIM;
  for (int d = 0; d < D_DIM; ++d) acc += sp[d] * w1r[d];
  sh[t] = fmaxf(acc, 0.0f);
  __syncthreads();
  if (t < E_DIM) {
    float a = b2[t];
    const float* w2r = W2 + t * H_DIM;
    for (int j = 0; j < H_DIM; ++j) a += sh[j] * w2r[j];
    slog[t] = a;
  }
  __syncthreads();
  if (t == 0) {
    float p[E_DIM];
    float mx = slog[0];
    for (int e = 1; e < E_DIM; ++e) mx = fmaxf(mx, slog[e]);
    float se = 0.0f;
    for (int e = 0; e < E_DIM; ++e) { p[e] = __expf(slog[e] - mx); se += p[e]; }
    float inv = 1.0f / se;
    for (int e = 0; e < E_DIM; ++e) { p[e] *= inv; probs_out[b * E_DIM + e] = p[e]; }
    // top-2, lowest index wins ties (strict > keeps earlier index)
    int i0 = 0;
    for (int e = 1; e < E_DIM; ++e) if (p[e] > p[i0]) i0 = e;
    int i1 = (i0 == 0) ? 1 : 0;
    for (int e = 0; e < E_DIM; ++e) if (e != i0 && p[e] > p[i1]) i1 = e;
    float s2 = p[i0] + p[i1];
    float invs = 1.0f / fmaxf(s2, 1e-6f);
    for (int e = 0; e < E_DIM; ++e) {
      float w = 0.0f;
      if (e == i0) w += p[i0] * invs;
      if (e == i1) w += p[i1] * invs;
      wfull[b * E_DIM + e] = w;
    }
  }
}

// ------- reduce partials over KSPLIT + combine: out = S_b + b_base + 2*Σ w·(S_l·B)
__global__ __launch_bounds__(256)
void reduce_combine_kernel(const float* __restrict__ P, const float* __restrict__ b_base,
                           const float* __restrict__ lora_B, const float* __restrict__ wfull,
                           float* __restrict__ out) {
  __shared__ float sS[RC_ROWS * N_TOTAL];   // 320 floats
  const int t = threadIdx.x;
  const size_t base = (size_t)blockIdx.x * (RC_ROWS * N_TOTAL);
  for (int s = t; s < RC_ROWS * N_TOTAL; s += 256) {
    const float* Pp = P + base + s;
    float a = 0.0f;
    #pragma unroll 8
    for (int k = 0; k < KSPLIT; ++k) a += Pp[(size_t)k * SMN];
    sS[s] = a;
  }
  __syncthreads();
  if (t < RC_ROWS * OUT_DIM) {
    int mr = t / OUT_DIM;
    int o = t - mr * OUT_DIM;
    int mm = blockIdx.x * RC_ROWS + mr;
    int b = mm / V_DIM;
    const float* srow = sS + mr * N_TOTAL;
    float res = srow[o] + b_base[o];
    float moe = 0.0f;
    #pragma unroll
    for (int e = 0; e < E_DIM; ++e) {
      float we = wfull[b * E_DIM + e];
      if (we != 0.0f) {
        const float* lb = lora_B + ((size_t)e * OUT_DIM + o) * R_DIM;
        float dd = 0.0f;
        #pragma unroll
        for (int r = 0; r < R_DIM; ++r) dd += srow[OUT_DIM + e * R_DIM + r] * lb[r];
        moe += we * dd;
      }
    }
    out[(size_t)mm * OUT_DIM + o] = res + SCALING * moe;
  }
}

extern "C" void kernel_launch(void* const* d_in, const int* in_sizes, int n_in,
                              void* d_out, int out_size, void* d_ws, size_t ws_size,
                              hipStream_t stream) {
  const float* x      = (const float*)d_in[0];
  const float* W_base = (const float*)d_in[1];
  const float* b_base = (const float*)d_in[2];
  const float* W1     = (const float*)d_in[3];
  const float* b1     = (const float*)d_in[4];
  const float* W2     = (const float*)d_in[5];
  const float* b2     = (const float*)d_in[6];
  const float* lora_A = (const float*)d_in[7];
  const float* lora_B = (const float*)d_in[8];
  float* out = (float*)d_out;

  // ws layout: pooled[16384 f] | wfull[256 f] | Wb[160*32768 bf16] | P[64*107520 f]
  float* ws     = (float*)d_ws;
  float* pooled = ws;
  float* wfull  = ws + 16384;
  short* Wb     = (short*)(wfull + 256);
  float* P      = (float*)(Wb + (size_t)N_TOTAL * K_TOTAL);

  convW_kernel<<<(N_TOTAL * K_TOTAL / 8 + 255) / 256, 256, 0, stream>>>(
      W_base, lora_A, Wb, pooled);
  gemm_kernel<<<dim3(11, KSPLIT), 256, 0, stream>>>(x, Wb, P, pooled);
  router_kernel<<<B_DIM, 256, 0, stream>>>(pooled, W1, b1, W2, b2, wfull,
                                           out + (size_t)M_TOTAL * OUT_DIM);
  reduce_combine_kernel<<<M_TOTAL / RC_ROWS, 256, 0, stream>>>(
      P, b_base, lora_B, wfull, out);
}